// Round 1
// baseline (303.685 us; speedup 1.0000x reference)
//
#include <hip/hip_runtime.h>
#include <hip/hip_bf16.h>

// Problem constants: B=2, T=2048, D=1024, H=16, HD=64
// M1 = B*T = 4096, K = 1024, N1 = 3*1024 = 3072

typedef __attribute__((ext_vector_type(8))) short bf16x8;
typedef __attribute__((ext_vector_type(4))) float f32x4;

__device__ __forceinline__ short f2b(float f) {
    union { float f; unsigned u; } in; in.f = f;
    unsigned u = in.u;
    unsigned r = (u + 0x7FFFu + ((u >> 16) & 1u)) >> 16;   // RNE
    return (short)r;
}

// ---------------------------------------------------------------------------
// Transpose + fp32->bf16 convert:  in[R][C] fp32  ->  out[C][R] bf16
// 64x64 tiles, 256 threads.
// ---------------------------------------------------------------------------
__global__ __launch_bounds__(256) void transpose_w_kernel(
    const float* __restrict__ in, short* __restrict__ out, int R, int C) {
    __shared__ short lds[64][72];
    const int t = threadIdx.x;
    const int r0 = blockIdx.y * 64, c0 = blockIdx.x * 64;
    {
        const int ri = t >> 2, cb = (t & 3) * 16;
        const float* src = in + (size_t)(r0 + ri) * C + c0 + cb;
#pragma unroll
        for (int i = 0; i < 16; i += 4) {
            float4 v = *reinterpret_cast<const float4*>(src + i);
            lds[cb + i + 0][ri] = f2b(v.x);
            lds[cb + i + 1][ri] = f2b(v.y);
            lds[cb + i + 2][ri] = f2b(v.z);
            lds[cb + i + 3][ri] = f2b(v.w);
        }
    }
    __syncthreads();
    {
        const int co = t >> 2, rb = (t & 3) * 16;
        short* dst = out + (size_t)(c0 + co) * R + r0 + rb;
        *reinterpret_cast<uint4*>(dst)     = *reinterpret_cast<const uint4*>(&lds[co][rb]);
        *reinterpret_cast<uint4*>(dst + 8) = *reinterpret_cast<const uint4*>(&lds[co][rb + 8]);
    }
}

// ---------------------------------------------------------------------------
// GEMM1: qkv = x @ Wqkv + bqkv     (A fp32 converted in staging, B^T bf16)
// M=4096 N=3072 K=1024. 128x128 tile, BK=32, 256 thr (4 waves 2x2 -> 64x64).
// Epilogue routes q,k -> [bh][t][64] and v -> transposed [bh][64][t].
// ---------------------------------------------------------------------------
__global__ __launch_bounds__(256) void gemm1_kernel(
    const float* __restrict__ X, const short* __restrict__ WT,
    const float* __restrict__ bqkv,
    short* __restrict__ qb, short* __restrict__ kb, short* __restrict__ vtb) {
    __shared__ short a_lds[128][40];
    __shared__ short b_lds[128][40];
    const int tid = threadIdx.x;
    const int lane = tid & 63, w = tid >> 6;
    const int wr = w >> 1, wc = w & 1;
    const int m0 = blockIdx.y * 128, n0 = blockIdx.x * 128;
    f32x4 acc[4][4] = {};

    for (int k0 = 0; k0 < 1024; k0 += 32) {
        __syncthreads();
#pragma unroll
        for (int rep = 0; rep < 2; ++rep) {
            const int e = rep * 256 + tid;
            const int row = e >> 2, c8 = (e & 3) * 8;
            // A: fp32 -> bf16
            const float* ap = X + (size_t)(m0 + row) * 1024 + k0 + c8;
            float4 v0 = *reinterpret_cast<const float4*>(ap);
            float4 v1 = *reinterpret_cast<const float4*>(ap + 4);
            union { short s[8]; uint4 q; } pk;
            pk.s[0] = f2b(v0.x); pk.s[1] = f2b(v0.y); pk.s[2] = f2b(v0.z); pk.s[3] = f2b(v0.w);
            pk.s[4] = f2b(v1.x); pk.s[5] = f2b(v1.y); pk.s[6] = f2b(v1.z); pk.s[7] = f2b(v1.w);
            *reinterpret_cast<uint4*>(&a_lds[row][c8]) = pk.q;
            // B: bf16 copy
            const short* bp = WT + (size_t)(n0 + row) * 1024 + k0 + c8;
            *reinterpret_cast<uint4*>(&b_lds[row][c8]) = *reinterpret_cast<const uint4*>(bp);
        }
        __syncthreads();
        bf16x8 af[4], bfv[4];
#pragma unroll
        for (int mi = 0; mi < 4; ++mi)
            af[mi] = *reinterpret_cast<const bf16x8*>(&a_lds[wr * 64 + mi * 16 + (lane & 15)][(lane >> 4) * 8]);
#pragma unroll
        for (int nj = 0; nj < 4; ++nj)
            bfv[nj] = *reinterpret_cast<const bf16x8*>(&b_lds[wc * 64 + nj * 16 + (lane & 15)][(lane >> 4) * 8]);
#pragma unroll
        for (int mi = 0; mi < 4; ++mi)
#pragma unroll
            for (int nj = 0; nj < 4; ++nj)
                acc[mi][nj] = __builtin_amdgcn_mfma_f32_16x16x32_bf16(af[mi], bfv[nj], acc[mi][nj], 0, 0, 0);
    }

    // Epilogue: C[row][col], row=(lane>>4)*4+r within 16-tile, col=lane&15
#pragma unroll
    for (int mi = 0; mi < 4; ++mi) {
#pragma unroll
        for (int nj = 0; nj < 4; ++nj) {
            const int row0 = m0 + wr * 64 + mi * 16 + ((lane >> 4) << 2);
            const int col  = n0 + wc * 64 + nj * 16 + (lane & 15);
            const float bias = bqkv[col];
            const int sec = col >> 10;
            const int h = (col & 1023) >> 6, d = col & 63;
            const int b = row0 >> 11;
            const int bh = b * 16 + h;
            if (sec == 2) {
                const int t0 = row0 & 2047;
                union { short s[4]; uint2 u; } pk;
#pragma unroll
                for (int r = 0; r < 4; ++r) pk.s[r] = f2b(acc[mi][nj][r] + bias);
                *reinterpret_cast<uint2*>(vtb + (size_t)(bh * 64 + d) * 2048 + t0) = pk.u;
            } else {
                short* dst = (sec == 0) ? qb : kb;
#pragma unroll
                for (int r = 0; r < 4; ++r) {
                    const int t = (row0 & 2047) + r;
                    dst[(size_t)(bh * 2048 + t) * 64 + d] = f2b(acc[mi][nj][r] + bias);
                }
            }
        }
    }
}

// ---------------------------------------------------------------------------
// Flash attention. Workgroup = (qblock of 64, h, b), 4 waves x 16 q-rows.
// KV tiles of 64. K and V^T staged in LDS (pad 72 elems -> <=2-way conflicts).
// Online softmax fp32; P -> bf16 via per-wave LDS bounce (D-layout->A-layout).
// ---------------------------------------------------------------------------
__global__ __launch_bounds__(256) void attn_kernel(
    const short* __restrict__ qb, const short* __restrict__ kb,
    const short* __restrict__ vtb, short* __restrict__ ctx) {
    __shared__ short k_lds[64][72];
    __shared__ short v_lds[64][72];
    __shared__ short p_lds[4][16][72];
    const int tid = threadIdx.x, lane = tid & 63, w = tid >> 6;
    const int h = blockIdx.y, b = blockIdx.z;
    const int bh = b * 16 + h;
    const int qbase = blockIdx.x * 64;

    // Q fragments straight from global (A-layout: row=lane&15, k=(lane>>4)*8+j)
    const int tq = qbase + w * 16 + (lane & 15);
    bf16x8 qf[2];
#pragma unroll
    for (int ks = 0; ks < 2; ++ks)
        qf[ks] = *reinterpret_cast<const bf16x8*>(
            qb + (size_t)(bh * 2048 + tq) * 64 + ks * 32 + ((lane >> 4) * 8));

    f32x4 o[4] = {};
    float m_r[4] = {-1e30f, -1e30f, -1e30f, -1e30f};
    float l_r[4] = {0.f, 0.f, 0.f, 0.f};

    for (int kv0 = 0; kv0 < 2048; kv0 += 64) {
        __syncthreads();
#pragma unroll
        for (int rep = 0; rep < 2; ++rep) {
            const int e = rep * 256 + tid;
            const int row = e >> 3, c8 = (e & 7) * 8;
            *reinterpret_cast<uint4*>(&k_lds[row][c8]) =
                *reinterpret_cast<const uint4*>(kb + (size_t)(bh * 2048 + kv0 + row) * 64 + c8);
            *reinterpret_cast<uint4*>(&v_lds[row][c8]) =
                *reinterpret_cast<const uint4*>(vtb + (size_t)(bh * 64 + row) * 2048 + kv0 + c8);
        }
        __syncthreads();

        // S = Q K^T  (B-frag = K rows, K-contiguous)
        f32x4 s[4] = {};
#pragma unroll
        for (int ks = 0; ks < 2; ++ks) {
#pragma unroll
            for (int nt = 0; nt < 4; ++nt) {
                bf16x8 kf = *reinterpret_cast<const bf16x8*>(
                    &k_lds[nt * 16 + (lane & 15)][ks * 32 + (lane >> 4) * 8]);
                s[nt] = __builtin_amdgcn_mfma_f32_16x16x32_bf16(qf[ks], kf, s[nt], 0, 0, 0);
            }
        }
#pragma unroll
        for (int nt = 0; nt < 4; ++nt) s[nt] *= 0.125f;   // 1/sqrt(64)

        // Online softmax. Row r_global=(lane>>4)*4+r, 16 cols per tile at lane&15.
        float alpha[4], rs[4];
#pragma unroll
        for (int r = 0; r < 4; ++r) {
            float v = fmaxf(fmaxf(s[0][r], s[1][r]), fmaxf(s[2][r], s[3][r]));
            v = fmaxf(v, __shfl_xor(v, 1));
            v = fmaxf(v, __shfl_xor(v, 2));
            v = fmaxf(v, __shfl_xor(v, 4));
            v = fmaxf(v, __shfl_xor(v, 8));
            const float mn = fmaxf(m_r[r], v);
            alpha[r] = __expf(m_r[r] - mn);
            m_r[r] = mn;
            rs[r] = 0.f;
        }
#pragma unroll
        for (int nt = 0; nt < 4; ++nt)
#pragma unroll
            for (int r = 0; r < 4; ++r) {
                const float p = __expf(s[nt][r] - m_r[r]);
                s[nt][r] = p;
                rs[r] += p;
            }
#pragma unroll
        for (int r = 0; r < 4; ++r) {
            float v = rs[r];
            v += __shfl_xor(v, 1);
            v += __shfl_xor(v, 2);
            v += __shfl_xor(v, 4);
            v += __shfl_xor(v, 8);
            l_r[r] = l_r[r] * alpha[r] + v;
            o[0][r] *= alpha[r]; o[1][r] *= alpha[r];
            o[2][r] *= alpha[r]; o[3][r] *= alpha[r];
        }

        // P (D-layout) -> LDS -> A-layout fragments
#pragma unroll
        for (int nt = 0; nt < 4; ++nt)
#pragma unroll
            for (int r = 0; r < 4; ++r)
                p_lds[w][(lane >> 4) * 4 + r][nt * 16 + (lane & 15)] = f2b(s[nt][r]);

        // O += P V   (B-frag from V^T rows, K-contiguous)
#pragma unroll
        for (int ks2 = 0; ks2 < 2; ++ks2) {
            bf16x8 pa = *reinterpret_cast<const bf16x8*>(
                &p_lds[w][lane & 15][ks2 * 32 + (lane >> 4) * 8]);
#pragma unroll
            for (int nt = 0; nt < 4; ++nt) {
                bf16x8 vf = *reinterpret_cast<const bf16x8*>(
                    &v_lds[nt * 16 + (lane & 15)][ks2 * 32 + (lane >> 4) * 8]);
                o[nt] = __builtin_amdgcn_mfma_f32_16x16x32_bf16(pa, vf, o[nt], 0, 0, 0);
            }
        }
    }

    // normalize + store ctx (bf16) at [b*T+t][h*64 + d]
#pragma unroll
    for (int r = 0; r < 4; ++r) {
        const float inv = 1.0f / l_r[r];
        const int trow = qbase + w * 16 + (lane >> 4) * 4 + r;
#pragma unroll
        for (int nt = 0; nt < 4; ++nt)
            ctx[(size_t)(b * 2048 + trow) * 1024 + h * 64 + nt * 16 + (lane & 15)] =
                f2b(o[nt][r] * inv);
    }
}

// ---------------------------------------------------------------------------
// GEMM2: out = ctx @ Wout + bout   (A bf16, B^T bf16, C fp32)
// M=4096 N=1024 K=1024. Same structure as GEMM1.
// ---------------------------------------------------------------------------
__global__ __launch_bounds__(256) void gemm2_kernel(
    const short* __restrict__ CTX, const short* __restrict__ WT,
    const float* __restrict__ bout, float* __restrict__ out) {
    __shared__ short a_lds[128][40];
    __shared__ short b_lds[128][40];
    const int tid = threadIdx.x;
    const int lane = tid & 63, w = tid >> 6;
    const int wr = w >> 1, wc = w & 1;
    const int m0 = blockIdx.y * 128, n0 = blockIdx.x * 128;
    f32x4 acc[4][4] = {};

    for (int k0 = 0; k0 < 1024; k0 += 32) {
        __syncthreads();
#pragma unroll
        for (int rep = 0; rep < 2; ++rep) {
            const int e = rep * 256 + tid;
            const int row = e >> 2, c8 = (e & 3) * 8;
            *reinterpret_cast<uint4*>(&a_lds[row][c8]) =
                *reinterpret_cast<const uint4*>(CTX + (size_t)(m0 + row) * 1024 + k0 + c8);
            *reinterpret_cast<uint4*>(&b_lds[row][c8]) =
                *reinterpret_cast<const uint4*>(WT + (size_t)(n0 + row) * 1024 + k0 + c8);
        }
        __syncthreads();
        bf16x8 af[4], bfv[4];
#pragma unroll
        for (int mi = 0; mi < 4; ++mi)
            af[mi] = *reinterpret_cast<const bf16x8*>(&a_lds[wr * 64 + mi * 16 + (lane & 15)][(lane >> 4) * 8]);
#pragma unroll
        for (int nj = 0; nj < 4; ++nj)
            bfv[nj] = *reinterpret_cast<const bf16x8*>(&b_lds[wc * 64 + nj * 16 + (lane & 15)][(lane >> 4) * 8]);
#pragma unroll
        for (int mi = 0; mi < 4; ++mi)
#pragma unroll
            for (int nj = 0; nj < 4; ++nj)
                acc[mi][nj] = __builtin_amdgcn_mfma_f32_16x16x32_bf16(af[mi], bfv[nj], acc[mi][nj], 0, 0, 0);
    }

#pragma unroll
    for (int mi = 0; mi < 4; ++mi) {
#pragma unroll
        for (int nj = 0; nj < 4; ++nj) {
            const int row0 = m0 + wr * 64 + mi * 16 + ((lane >> 4) << 2);
            const int col  = n0 + wc * 64 + nj * 16 + (lane & 15);
            const float bias = bout[col];
#pragma unroll
            for (int r = 0; r < 4; ++r)
                out[(size_t)(row0 + r) * 1024 + col] = acc[mi][nj][r] + bias;
        }
    }
}

// ---------------------------------------------------------------------------
extern "C" void kernel_launch(void* const* d_in, const int* in_sizes, int n_in,
                              void* d_out, int out_size, void* d_ws, size_t ws_size,
                              hipStream_t stream) {
    const float* x    = (const float*)d_in[0];
    const float* Wqkv = (const float*)d_in[1];
    const float* bqkv = (const float*)d_in[2];
    const float* Wout = (const float*)d_in[3];
    const float* bout = (const float*)d_in[4];
    float* out = (float*)d_out;

    const size_t MB = 1u << 20;
    if (ws_size < 40 * MB) return;   // fail visibly rather than corrupt

    char* ws = (char*)d_ws;
    short* qb    = (short*)(ws + 0 * MB);    // [2][16][2048][64] bf16  (8 MB)
    short* kb    = (short*)(ws + 8 * MB);    // [2][16][2048][64] bf16  (8 MB)
    short* vtb   = (short*)(ws + 16 * MB);   // [2][16][64][2048] bf16  (8 MB)
    short* ctx   = (short*)(ws + 24 * MB);   // [4096][1024] bf16       (8 MB)
    short* wqkvT = (short*)(ws + 32 * MB);   // [3072][1024] bf16       (6 MB)
    short* woutT = (short*)(ws + 38 * MB);   // [1024][1024] bf16       (2 MB)

    transpose_w_kernel<<<dim3(48, 16), 256, 0, stream>>>(Wqkv, wqkvT, 1024, 3072);
    transpose_w_kernel<<<dim3(16, 16), 256, 0, stream>>>(Wout, woutT, 1024, 1024);
    gemm1_kernel<<<dim3(24, 32), 256, 0, stream>>>(x, wqkvT, bqkv, qb, kb, vtb);
    attn_kernel<<<dim3(32, 16, 2), 256, 0, stream>>>(qb, kb, vtb, ctx);
    gemm2_kernel<<<dim3(8, 32), 256, 0, stream>>>(ctx, woutT, bout, out);
}

// Round 2
// 265.819 us; speedup vs baseline: 1.1425x; 1.1425x over previous
//
#include <hip/hip_runtime.h>
#include <hip/hip_bf16.h>

// Problem constants: B=2, T=2048, D=1024, H=16, HD=64
// M1 = B*T = 4096, K = 1024, N1 = 3*1024 = 3072

typedef __attribute__((ext_vector_type(8))) short bf16x8;
typedef __attribute__((ext_vector_type(4))) float f32x4;

__device__ __forceinline__ short f2b(float f) {
    __hip_bfloat16 h = __float2bfloat16(f);
    union { __hip_bfloat16 h; short s; } u; u.h = h;
    return u.s;
}

#define GLOAD_LDS16(gp, lp)                                                        \
    __builtin_amdgcn_global_load_lds(                                              \
        (const __attribute__((address_space(1))) unsigned int*)(gp),               \
        (__attribute__((address_space(3))) unsigned int*)(lp), 16, 0, 0)

// ---------------------------------------------------------------------------
// x fp32 -> bf16, 8 elements/thread
// ---------------------------------------------------------------------------
__global__ __launch_bounds__(256) void xcvt_kernel(
    const float* __restrict__ in, short* __restrict__ out) {
    const int i = (blockIdx.x * 256 + threadIdx.x) * 8;
    float4 v0 = *reinterpret_cast<const float4*>(in + i);
    float4 v1 = *reinterpret_cast<const float4*>(in + i + 4);
    union { short s[8]; uint4 q; } pk;
    pk.s[0] = f2b(v0.x); pk.s[1] = f2b(v0.y); pk.s[2] = f2b(v0.z); pk.s[3] = f2b(v0.w);
    pk.s[4] = f2b(v1.x); pk.s[5] = f2b(v1.y); pk.s[6] = f2b(v1.z); pk.s[7] = f2b(v1.w);
    *reinterpret_cast<uint4*>(out + i) = pk.q;
}

// ---------------------------------------------------------------------------
// Transpose + fp32->bf16 convert:  in[R][C] fp32  ->  out[C][R] bf16
// ---------------------------------------------------------------------------
__global__ __launch_bounds__(256) void transpose_w_kernel(
    const float* __restrict__ in, short* __restrict__ out, int R, int C) {
    __shared__ short lds[64][72];
    const int t = threadIdx.x;
    const int r0 = blockIdx.y * 64, c0 = blockIdx.x * 64;
    {
        const int ri = t >> 2, cb = (t & 3) * 16;
        const float* src = in + (size_t)(r0 + ri) * C + c0 + cb;
#pragma unroll
        for (int i = 0; i < 16; i += 4) {
            float4 v = *reinterpret_cast<const float4*>(src + i);
            lds[cb + i + 0][ri] = f2b(v.x);
            lds[cb + i + 1][ri] = f2b(v.y);
            lds[cb + i + 2][ri] = f2b(v.z);
            lds[cb + i + 3][ri] = f2b(v.w);
        }
    }
    __syncthreads();
    {
        const int co = t >> 2, rb = (t & 3) * 16;
        short* dst = out + (size_t)(c0 + co) * R + r0 + rb;
        *reinterpret_cast<uint4*>(dst)     = *reinterpret_cast<const uint4*>(&lds[co][rb]);
        *reinterpret_cast<uint4*>(dst + 8) = *reinterpret_cast<const uint4*>(&lds[co][rb + 8]);
    }
}

// ---------------------------------------------------------------------------
// GEMM1: qkv = xb @ WqkvT^T + bqkv   (all bf16 in, fp32 acc)
// M=4096 N=3072 K=1024. 128x128 tile, BK=32, 4 waves (2x2 of 64x64).
// global_load_lds staging, slot-XOR swizzle (phys_slot = slot ^ ((row>>1)&3)).
// Epilogue scatters q,k -> [bh][t][64] and v -> [bh][64][t] (transposed).
// ---------------------------------------------------------------------------
__global__ __launch_bounds__(256) void gemm1_kernel(
    const short* __restrict__ XB, const short* __restrict__ WT,
    const float* __restrict__ bqkv,
    short* __restrict__ qb, short* __restrict__ kb, short* __restrict__ vtb) {
    __shared__ short a_lds[128 * 32];
    __shared__ short b_lds[128 * 32];
    const int tid = threadIdx.x;
    const int lane = tid & 63, w = tid >> 6;
    const int wr = w >> 1, wc = w & 1;
    const int m0 = blockIdx.y * 128, n0 = blockIdx.x * 128;
    f32x4 acc[4][4] = {};

    for (int k0 = 0; k0 < 1024; k0 += 32) {
        __syncthreads();
#pragma unroll
        for (int rep = 0; rep < 2; ++rep) {
            const int e = rep * 256 + tid;
            const int row = e >> 2, sl = e & 3;
            const int lc = (sl ^ ((row >> 1) & 3)) * 8;   // inverse-swizzled source
            short* ldsbase_a = a_lds + (rep * 256 + w * 64) * 8;
            short* ldsbase_b = b_lds + (rep * 256 + w * 64) * 8;
            GLOAD_LDS16(XB + (size_t)(m0 + row) * 1024 + k0 + lc, ldsbase_a);
            GLOAD_LDS16(WT + (size_t)(n0 + row) * 1024 + k0 + lc, ldsbase_b);
        }
        __syncthreads();
        bf16x8 af[4], bfv[4];
#pragma unroll
        for (int mi = 0; mi < 4; ++mi) {
            const int rA = wr * 64 + mi * 16 + (lane & 15);
            const int sl = (lane >> 4) ^ ((rA >> 1) & 3);
            af[mi] = *reinterpret_cast<const bf16x8*>(&a_lds[rA * 32 + sl * 8]);
        }
#pragma unroll
        for (int nj = 0; nj < 4; ++nj) {
            const int rB = wc * 64 + nj * 16 + (lane & 15);
            const int sl = (lane >> 4) ^ ((rB >> 1) & 3);
            bfv[nj] = *reinterpret_cast<const bf16x8*>(&b_lds[rB * 32 + sl * 8]);
        }
#pragma unroll
        for (int mi = 0; mi < 4; ++mi)
#pragma unroll
            for (int nj = 0; nj < 4; ++nj)
                acc[mi][nj] = __builtin_amdgcn_mfma_f32_16x16x32_bf16(af[mi], bfv[nj], acc[mi][nj], 0, 0, 0);
    }

    // Epilogue: C[row][col], row=(lane>>4)*4+r within 16-tile, col=lane&15
#pragma unroll
    for (int mi = 0; mi < 4; ++mi) {
#pragma unroll
        for (int nj = 0; nj < 4; ++nj) {
            const int row0 = m0 + wr * 64 + mi * 16 + ((lane >> 4) << 2);
            const int col  = n0 + wc * 64 + nj * 16 + (lane & 15);
            const float bias = bqkv[col];
            const int sec = col >> 10;
            const int h = (col & 1023) >> 6, d = col & 63;
            const int b = row0 >> 11;
            const int bh = b * 16 + h;
            if (sec == 2) {
                const int t0 = row0 & 2047;
                union { short s[4]; uint2 u; } pk;
#pragma unroll
                for (int r = 0; r < 4; ++r) pk.s[r] = f2b(acc[mi][nj][r] + bias);
                *reinterpret_cast<uint2*>(vtb + (size_t)(bh * 64 + d) * 2048 + t0) = pk.u;
            } else {
                short* dst = (sec == 0) ? qb : kb;
#pragma unroll
                for (int r = 0; r < 4; ++r) {
                    const int t = (row0 & 2047) + r;
                    dst[(size_t)(bh * 2048 + t) * 64 + d] = f2b(acc[mi][nj][r] + bias);
                }
            }
        }
    }
}

// ---------------------------------------------------------------------------
// Flash attention. Workgroup = (qblock of 64, h, b), 4 waves x 16 q-rows.
// KV tiles of 64. K and V^T in linear LDS [64][64] staged by global_load_lds
// with XOR-swizzled source (byte ^= (row&7)<<4); frag reads apply same XOR.
// Online softmax in log2 domain; P bounced via per-wave LDS (stride 68).
// ---------------------------------------------------------------------------
__global__ __launch_bounds__(256) void attn_kernel(
    const short* __restrict__ qb, const short* __restrict__ kb,
    const short* __restrict__ vtb, short* __restrict__ ctx) {
    __shared__ short k_lds[64 * 64];
    __shared__ short v_lds[64 * 64];
    __shared__ short p_lds[4][16][68];
    const int tid = threadIdx.x, lane = tid & 63, w = tid >> 6;
    const int h = blockIdx.y, b = blockIdx.z;
    const int bh = b * 16 + h;
    const int qbase = blockIdx.x * 64;

    // Q fragments straight from global (A-layout: row=lane&15, k=(lane>>4)*8+j)
    const int tq = qbase + w * 16 + (lane & 15);
    bf16x8 qf[2];
#pragma unroll
    for (int ks = 0; ks < 2; ++ks)
        qf[ks] = *reinterpret_cast<const bf16x8*>(
            qb + (size_t)(bh * 2048 + tq) * 64 + ks * 32 + ((lane >> 4) * 8));

    f32x4 o[4] = {};
    float m_r[4] = {-1e30f, -1e30f, -1e30f, -1e30f};
    float l_r[4] = {0.f, 0.f, 0.f, 0.f};
    const float SCL = 0.125f * 1.44269504088896340736f;   // 1/sqrt(64) * log2(e)

    for (int kv0 = 0; kv0 < 2048; kv0 += 64) {
        __syncthreads();
#pragma unroll
        for (int rep = 0; rep < 2; ++rep) {
            const int e = rep * 256 + tid;
            const int row = e >> 3, sl = e & 7;
            const int lc = (sl ^ (row & 7)) * 8;          // inverse-swizzled source
            short* ldsbase_k = k_lds + (rep * 256 + w * 64) * 8;
            short* ldsbase_v = v_lds + (rep * 256 + w * 64) * 8;
            GLOAD_LDS16(kb + (size_t)(bh * 2048 + kv0 + row) * 64 + lc, ldsbase_k);
            GLOAD_LDS16(vtb + (size_t)(bh * 64 + row) * 2048 + kv0 + lc, ldsbase_v);
        }
        __syncthreads();

        // S = Q K^T  (B-frag = K rows, K-contiguous, swizzled read)
        f32x4 s[4] = {};
#pragma unroll
        for (int ks = 0; ks < 2; ++ks) {
#pragma unroll
            for (int nt = 0; nt < 4; ++nt) {
                const int rK = nt * 16 + (lane & 15);
                const int sl = (ks * 4 + (lane >> 4)) ^ (rK & 7);
                bf16x8 kf = *reinterpret_cast<const bf16x8*>(&k_lds[rK * 64 + sl * 8]);
                s[nt] = __builtin_amdgcn_mfma_f32_16x16x32_bf16(qf[ks], kf, s[nt], 0, 0, 0);
            }
        }
#pragma unroll
        for (int nt = 0; nt < 4; ++nt) s[nt] *= SCL;      // log2 domain

        // Online softmax. Element: q=(lane>>4)*4+r, k=nt*16+(lane&15).
        float alpha[4], rs[4];
#pragma unroll
        for (int r = 0; r < 4; ++r) {
            float v = fmaxf(fmaxf(s[0][r], s[1][r]), fmaxf(s[2][r], s[3][r]));
            v = fmaxf(v, __shfl_xor(v, 1));
            v = fmaxf(v, __shfl_xor(v, 2));
            v = fmaxf(v, __shfl_xor(v, 4));
            v = fmaxf(v, __shfl_xor(v, 8));
            const float mn = fmaxf(m_r[r], v);
            alpha[r] = exp2f(m_r[r] - mn);
            m_r[r] = mn;
            rs[r] = 0.f;
        }
#pragma unroll
        for (int nt = 0; nt < 4; ++nt)
#pragma unroll
            for (int r = 0; r < 4; ++r) {
                const float p = exp2f(s[nt][r] - m_r[r]);
                s[nt][r] = p;
                rs[r] += p;
            }
#pragma unroll
        for (int r = 0; r < 4; ++r) {
            float v = rs[r];
            v += __shfl_xor(v, 1);
            v += __shfl_xor(v, 2);
            v += __shfl_xor(v, 4);
            v += __shfl_xor(v, 8);
            l_r[r] = l_r[r] * alpha[r] + v;
            o[0][r] *= alpha[r]; o[1][r] *= alpha[r];
            o[2][r] *= alpha[r]; o[3][r] *= alpha[r];
        }

        // P (D-layout) -> LDS -> A-layout fragments
#pragma unroll
        for (int nt = 0; nt < 4; ++nt)
#pragma unroll
            for (int r = 0; r < 4; ++r)
                p_lds[w][(lane >> 4) * 4 + r][nt * 16 + (lane & 15)] = f2b(s[nt][r]);

        // O += P V   (B-frag from V^T rows, K-contiguous, swizzled read)
#pragma unroll
        for (int ks2 = 0; ks2 < 2; ++ks2) {
            bf16x8 pa = *reinterpret_cast<const bf16x8*>(
                &p_lds[w][lane & 15][ks2 * 32 + (lane >> 4) * 8]);
#pragma unroll
            for (int nt = 0; nt < 4; ++nt) {
                const int rV = nt * 16 + (lane & 15);
                const int sl = (ks2 * 4 + (lane >> 4)) ^ (rV & 7);
                bf16x8 vf = *reinterpret_cast<const bf16x8*>(&v_lds[rV * 64 + sl * 8]);
                o[nt] = __builtin_amdgcn_mfma_f32_16x16x32_bf16(pa, vf, o[nt], 0, 0, 0);
            }
        }
    }

    // normalize + store ctx (bf16) at [b*T+t][h*64 + d]
#pragma unroll
    for (int r = 0; r < 4; ++r) {
        const float inv = 1.0f / l_r[r];
        const int trow = qbase + w * 16 + (lane >> 4) * 4 + r;
#pragma unroll
        for (int nt = 0; nt < 4; ++nt)
            ctx[(size_t)(b * 2048 + trow) * 1024 + h * 64 + nt * 16 + (lane & 15)] =
                f2b(o[nt][r] * inv);
    }
}

// ---------------------------------------------------------------------------
// GEMM2: out = ctx @ WoutT^T + bout   (A bf16, B^T bf16, C fp32)
// M=4096 N=1024 K=1024. Same structure as GEMM1.
// ---------------------------------------------------------------------------
__global__ __launch_bounds__(256) void gemm2_kernel(
    const short* __restrict__ CTX, const short* __restrict__ WT,
    const float* __restrict__ bout, float* __restrict__ out) {
    __shared__ short a_lds[128 * 32];
    __shared__ short b_lds[128 * 32];
    const int tid = threadIdx.x;
    const int lane = tid & 63, w = tid >> 6;
    const int wr = w >> 1, wc = w & 1;
    const int m0 = blockIdx.y * 128, n0 = blockIdx.x * 128;
    f32x4 acc[4][4] = {};

    for (int k0 = 0; k0 < 1024; k0 += 32) {
        __syncthreads();
#pragma unroll
        for (int rep = 0; rep < 2; ++rep) {
            const int e = rep * 256 + tid;
            const int row = e >> 2, sl = e & 3;
            const int lc = (sl ^ ((row >> 1) & 3)) * 8;
            short* ldsbase_a = a_lds + (rep * 256 + w * 64) * 8;
            short* ldsbase_b = b_lds + (rep * 256 + w * 64) * 8;
            GLOAD_LDS16(CTX + (size_t)(m0 + row) * 1024 + k0 + lc, ldsbase_a);
            GLOAD_LDS16(WT + (size_t)(n0 + row) * 1024 + k0 + lc, ldsbase_b);
        }
        __syncthreads();
        bf16x8 af[4], bfv[4];
#pragma unroll
        for (int mi = 0; mi < 4; ++mi) {
            const int rA = wr * 64 + mi * 16 + (lane & 15);
            const int sl = (lane >> 4) ^ ((rA >> 1) & 3);
            af[mi] = *reinterpret_cast<const bf16x8*>(&a_lds[rA * 32 + sl * 8]);
        }
#pragma unroll
        for (int nj = 0; nj < 4; ++nj) {
            const int rB = wc * 64 + nj * 16 + (lane & 15);
            const int sl = (lane >> 4) ^ ((rB >> 1) & 3);
            bfv[nj] = *reinterpret_cast<const bf16x8*>(&b_lds[rB * 32 + sl * 8]);
        }
#pragma unroll
        for (int mi = 0; mi < 4; ++mi)
#pragma unroll
            for (int nj = 0; nj < 4; ++nj)
                acc[mi][nj] = __builtin_amdgcn_mfma_f32_16x16x32_bf16(af[mi], bfv[nj], acc[mi][nj], 0, 0, 0);
    }

#pragma unroll
    for (int mi = 0; mi < 4; ++mi) {
#pragma unroll
        for (int nj = 0; nj < 4; ++nj) {
            const int row0 = m0 + wr * 64 + mi * 16 + ((lane >> 4) << 2);
            const int col  = n0 + wc * 64 + nj * 16 + (lane & 15);
            const float bias = bout[col];
#pragma unroll
            for (int r = 0; r < 4; ++r)
                out[(size_t)(row0 + r) * 1024 + col] = acc[mi][nj][r] + bias;
        }
    }
}

// ---------------------------------------------------------------------------
extern "C" void kernel_launch(void* const* d_in, const int* in_sizes, int n_in,
                              void* d_out, int out_size, void* d_ws, size_t ws_size,
                              hipStream_t stream) {
    const float* x    = (const float*)d_in[0];
    const float* Wqkv = (const float*)d_in[1];
    const float* bqkv = (const float*)d_in[2];
    const float* Wout = (const float*)d_in[3];
    const float* bout = (const float*)d_in[4];
    float* out = (float*)d_out;

    const size_t MB = 1u << 20;
    if (ws_size < 40 * MB) return;   // fail visibly rather than corrupt

    char* ws = (char*)d_ws;
    short* qb    = (short*)(ws + 0 * MB);    // [2][16][2048][64] bf16  (8 MB)
    short* kb    = (short*)(ws + 8 * MB);    // [2][16][2048][64] bf16  (8 MB)
    short* vtb   = (short*)(ws + 16 * MB);   // [2][16][64][2048] bf16  (8 MB)
    short* xbctx = (short*)(ws + 24 * MB);   // xb for gemm1, then ctx  (8 MB)
    short* wqkvT = (short*)(ws + 32 * MB);   // [3072][1024] bf16       (6 MB)
    short* woutT = (short*)(ws + 38 * MB);   // [1024][1024] bf16       (2 MB)

    xcvt_kernel<<<2048, 256, 0, stream>>>(x, xbctx);
    transpose_w_kernel<<<dim3(48, 16), 256, 0, stream>>>(Wqkv, wqkvT, 1024, 3072);
    transpose_w_kernel<<<dim3(16, 16), 256, 0, stream>>>(Wout, woutT, 1024, 1024);
    gemm1_kernel<<<dim3(24, 32), 256, 0, stream>>>(xbctx, wqkvT, bqkv, qb, kb, vtb);
    attn_kernel<<<dim3(32, 16, 2), 256, 0, stream>>>(qb, kb, vtb, xbctx);
    gemm2_kernel<<<dim3(8, 32), 256, 0, stream>>>(xbctx, woutT, bout, out);
}

// Round 3
// 215.796 us; speedup vs baseline: 1.4073x; 1.2318x over previous
//
#include <hip/hip_runtime.h>
#include <hip/hip_bf16.h>

// Problem constants: B=2, T=2048, D=1024, H=16, HD=64

typedef __attribute__((ext_vector_type(8))) short bf16x8;
typedef __attribute__((ext_vector_type(4))) float f32x4;

__device__ __forceinline__ short f2b(float f) {
    __hip_bfloat16 h = __float2bfloat16(f);
    union { __hip_bfloat16 h; short s; } u; u.h = h;
    return u.s;
}

#define GLOAD_LDS16(gp, lp)                                                        \
    __builtin_amdgcn_global_load_lds(                                              \
        (const __attribute__((address_space(1))) unsigned int*)(gp),               \
        (__attribute__((address_space(3))) unsigned int*)(lp), 16, 0, 0)

// ---------------------------------------------------------------------------
// x fp32 -> bf16, 8 elements/thread
// ---------------------------------------------------------------------------
__global__ __launch_bounds__(256) void xcvt_kernel(
    const float* __restrict__ in, short* __restrict__ out) {
    const int i = (blockIdx.x * 256 + threadIdx.x) * 8;
    float4 v0 = *reinterpret_cast<const float4*>(in + i);
    float4 v1 = *reinterpret_cast<const float4*>(in + i + 4);
    union { short s[8]; uint4 q; } pk;
    pk.s[0] = f2b(v0.x); pk.s[1] = f2b(v0.y); pk.s[2] = f2b(v0.z); pk.s[3] = f2b(v0.w);
    pk.s[4] = f2b(v1.x); pk.s[5] = f2b(v1.y); pk.s[6] = f2b(v1.z); pk.s[7] = f2b(v1.w);
    *reinterpret_cast<uint4*>(out + i) = pk.q;
}

// ---------------------------------------------------------------------------
// Transpose + fp32->bf16 convert:  in[R][C] fp32  ->  out[C][R] bf16
// ---------------------------------------------------------------------------
__global__ __launch_bounds__(256) void transpose_w_kernel(
    const float* __restrict__ in, short* __restrict__ out, int R, int C) {
    __shared__ short lds[64][72];
    const int t = threadIdx.x;
    const int r0 = blockIdx.y * 64, c0 = blockIdx.x * 64;
    {
        const int ri = t >> 2, cb = (t & 3) * 16;
        const float* src = in + (size_t)(r0 + ri) * C + c0 + cb;
#pragma unroll
        for (int i = 0; i < 16; i += 4) {
            float4 v = *reinterpret_cast<const float4*>(src + i);
            lds[cb + i + 0][ri] = f2b(v.x);
            lds[cb + i + 1][ri] = f2b(v.y);
            lds[cb + i + 2][ri] = f2b(v.z);
            lds[cb + i + 3][ri] = f2b(v.w);
        }
    }
    __syncthreads();
    {
        const int co = t >> 2, rb = (t & 3) * 16;
        short* dst = out + (size_t)(c0 + co) * R + r0 + rb;
        *reinterpret_cast<uint4*>(dst)     = *reinterpret_cast<const uint4*>(&lds[co][rb]);
        *reinterpret_cast<uint4*>(dst + 8) = *reinterpret_cast<const uint4*>(&lds[co][rb + 8]);
    }
}

// ---------------------------------------------------------------------------
// GEMM1: qkv = xb @ WqkvT^T + bqkv   (bf16 in, fp32 acc)
// 128x128 tile, BK=32, 4 waves. 2-phase double-buffered global_load_lds.
// Q is pre-scaled by 0.125*log2(e) so attn softmax runs in log2 domain.
// Epilogue: q,k -> [bh][t][64]; v -> [bh][64][t] (transposed).
// ---------------------------------------------------------------------------
__global__ __launch_bounds__(256) void gemm1_kernel(
    const short* __restrict__ XB, const short* __restrict__ WT,
    const float* __restrict__ bqkv,
    short* __restrict__ qb, short* __restrict__ kb, short* __restrict__ vtb) {
    __shared__ short a_lds[2][128 * 32];
    __shared__ short b_lds[2][128 * 32];
    const int tid = threadIdx.x;
    const int lane = tid & 63, w = tid >> 6;
    const int wr = w >> 1, wc = w & 1;
    const int m0 = blockIdx.y * 128, n0 = blockIdx.x * 128;
    f32x4 acc[4][4] = {};

    const int srow0 = tid >> 2, ssl = tid & 3;           // rep 0: rows 0..63
    const int slc0 = (ssl ^ ((srow0 >> 1) & 3)) * 8;
    const int srow1 = srow0 + 64;                        // rep 1: rows 64..127
    const int slc1 = (ssl ^ ((srow1 >> 1) & 3)) * 8;

#define G1_STAGE(bufi, kk)                                                          \
    do {                                                                            \
        GLOAD_LDS16(XB + (size_t)(m0 + srow0) * 1024 + (kk) + slc0,                 \
                    &a_lds[bufi][(w * 64) * 8]);                                    \
        GLOAD_LDS16(WT + (size_t)(n0 + srow0) * 1024 + (kk) + slc0,                 \
                    &b_lds[bufi][(w * 64) * 8]);                                    \
        GLOAD_LDS16(XB + (size_t)(m0 + srow1) * 1024 + (kk) + slc1,                 \
                    &a_lds[bufi][(256 + w * 64) * 8]);                              \
        GLOAD_LDS16(WT + (size_t)(n0 + srow1) * 1024 + (kk) + slc1,                 \
                    &b_lds[bufi][(256 + w * 64) * 8]);                              \
    } while (0)

    G1_STAGE(0, 0);
    __syncthreads();
    int cur = 0;
    for (int k0 = 0; k0 < 1024; k0 += 32) {
        if (k0 + 32 < 1024) G1_STAGE(cur ^ 1, k0 + 32);
        bf16x8 af[4], bfv[4];
#pragma unroll
        for (int mi = 0; mi < 4; ++mi) {
            const int rA = wr * 64 + mi * 16 + (lane & 15);
            const int sl = (lane >> 4) ^ ((rA >> 1) & 3);
            af[mi] = *reinterpret_cast<const bf16x8*>(&a_lds[cur][rA * 32 + sl * 8]);
        }
#pragma unroll
        for (int nj = 0; nj < 4; ++nj) {
            const int rB = wc * 64 + nj * 16 + (lane & 15);
            const int sl = (lane >> 4) ^ ((rB >> 1) & 3);
            bfv[nj] = *reinterpret_cast<const bf16x8*>(&b_lds[cur][rB * 32 + sl * 8]);
        }
#pragma unroll
        for (int mi = 0; mi < 4; ++mi)
#pragma unroll
            for (int nj = 0; nj < 4; ++nj)
                acc[mi][nj] = __builtin_amdgcn_mfma_f32_16x16x32_bf16(af[mi], bfv[nj], acc[mi][nj], 0, 0, 0);
        __syncthreads();
        cur ^= 1;
    }

    const float QSCL = 0.125f * 1.44269504088896340736f;   // 1/sqrt(64)*log2(e)
#pragma unroll
    for (int mi = 0; mi < 4; ++mi) {
#pragma unroll
        for (int nj = 0; nj < 4; ++nj) {
            const int row0 = m0 + wr * 64 + mi * 16 + ((lane >> 4) << 2);
            const int col  = n0 + wc * 64 + nj * 16 + (lane & 15);
            const float bias = bqkv[col];
            const int sec = col >> 10;
            const int h = (col & 1023) >> 6, d = col & 63;
            const int b = row0 >> 11;
            const int bh = b * 16 + h;
            if (sec == 2) {
                const int t0 = row0 & 2047;
                union { short s[4]; uint2 u; } pk;
#pragma unroll
                for (int r = 0; r < 4; ++r) pk.s[r] = f2b(acc[mi][nj][r] + bias);
                *reinterpret_cast<uint2*>(vtb + (size_t)(bh * 64 + d) * 2048 + t0) = pk.u;
            } else if (sec == 0) {
#pragma unroll
                for (int r = 0; r < 4; ++r) {
                    const int t = (row0 & 2047) + r;
                    qb[(size_t)(bh * 2048 + t) * 64 + d] = f2b((acc[mi][nj][r] + bias) * QSCL);
                }
            } else {
#pragma unroll
                for (int r = 0; r < 4; ++r) {
                    const int t = (row0 & 2047) + r;
                    kb[(size_t)(bh * 2048 + t) * 64 + d] = f2b(acc[mi][nj][r] + bias);
                }
            }
        }
    }
}

// ---------------------------------------------------------------------------
// Flash attention, swapped-QK^T structure.
// WG = 512 thr (8 waves), QBLK=128 (16 q-rows/wave), KVBLK=64.
// K,V double-buffered (2-phase: stage t+1, compute t, one barrier/iter).
// S^T = mfma(K,Q): lane holds 16 S-values of ONE q-row -> in-lane softmax
// (+2 shfl_xor), per-lane scalar m,l, defer-max THR=8 (log2 domain; Q
// pre-scaled). P packed as uint2 -> b64 LDS writes -> b128 A-frag reads.
// ---------------------------------------------------------------------------
__global__ __launch_bounds__(512) void attn_kernel(
    const short* __restrict__ qb, const short* __restrict__ kb,
    const short* __restrict__ vtb, short* __restrict__ ctx) {
    __shared__ short k_lds[2][64 * 64];
    __shared__ short v_lds[2][64 * 64];
    __shared__ short p_lds[8][16][68];
    const int tid = threadIdx.x, lane = tid & 63, w = tid >> 6;
    const int g = lane >> 4, qh = lane & 15;
    const int h = blockIdx.y, b = blockIdx.z, bh = b * 16 + h;
    const int qbase = blockIdx.x * 128;
    const int tq = qbase + w * 16 + qh;

    bf16x8 qf[2];
#pragma unroll
    for (int ks = 0; ks < 2; ++ks)
        qf[ks] = *reinterpret_cast<const bf16x8*>(
            qb + (size_t)(bh * 2048 + tq) * 64 + ks * 32 + g * 8);

    const int srow = tid >> 3, ssl = tid & 7;
    const int slc = (ssl ^ (srow & 7)) * 8;              // inverse-swizzled source

#define ATT_STAGE(bufi, kv)                                                         \
    do {                                                                            \
        GLOAD_LDS16(kb + (size_t)(bh * 2048 + (kv) + srow) * 64 + slc,              \
                    &k_lds[bufi][w * 512]);                                         \
        GLOAD_LDS16(vtb + (size_t)(bh * 64 + srow) * 2048 + (kv) + slc,             \
                    &v_lds[bufi][w * 512]);                                         \
    } while (0)

    f32x4 o[4] = {};
    float m_s = -1e30f, l_s = 0.f;

    ATT_STAGE(0, 0);
    __syncthreads();
    int cur = 0;
    for (int kv0 = 0; kv0 < 2048; kv0 += 64) {
        if (kv0 + 64 < 2048) ATT_STAGE(cur ^ 1, kv0 + 64);

        // S^T = K Q^T : s[nt][r] = score(q=tq, kv=kv0+nt*16+4g+r), log2-scaled
        f32x4 s[4] = {};
#pragma unroll
        for (int ks = 0; ks < 2; ++ks)
#pragma unroll
            for (int nt = 0; nt < 4; ++nt) {
                const int rK = nt * 16 + qh;
                const int sl = (ks * 4 + g) ^ (rK & 7);
                bf16x8 kf = *reinterpret_cast<const bf16x8*>(&k_lds[cur][rK * 64 + sl * 8]);
                s[nt] = __builtin_amdgcn_mfma_f32_16x16x32_bf16(kf, qf[ks], s[nt], 0, 0, 0);
            }

        // in-lane row max + cross-group combine
        float mx = s[0][0];
#pragma unroll
        for (int nt = 0; nt < 4; ++nt)
#pragma unroll
            for (int r = 0; r < 4; ++r) mx = fmaxf(mx, s[nt][r]);
        mx = fmaxf(mx, __shfl_xor(mx, 16));
        mx = fmaxf(mx, __shfl_xor(mx, 32));
        const float mn = fmaxf(m_s, mx);
        if (__any(mn - m_s > 8.f)) {                      // defer-max (T13)
            const float alpha = exp2f(m_s - mn);
            m_s = mn;
            l_s *= alpha;
#pragma unroll
            for (int r = 0; r < 4; ++r) {
                const float ar = __shfl(alpha, g * 4 + r);
                o[0][r] *= ar; o[1][r] *= ar; o[2][r] *= ar; o[3][r] *= ar;
            }
        }

        float rs = 0.f;
#pragma unroll
        for (int nt = 0; nt < 4; ++nt) {
            union { short s4[4]; uint2 u; } P;
#pragma unroll
            for (int r = 0; r < 4; ++r) {
                const float p = exp2f(s[nt][r] - m_s);
                rs += p;
                P.s4[r] = f2b(p);
            }
            *reinterpret_cast<uint2*>(&p_lds[w][qh][nt * 16 + 4 * g]) = P.u;
        }
        rs += __shfl_xor(rs, 16);
        rs += __shfl_xor(rs, 32);
        l_s += rs;

        // O += P V
#pragma unroll
        for (int ks2 = 0; ks2 < 2; ++ks2) {
            bf16x8 pa = *reinterpret_cast<const bf16x8*>(&p_lds[w][qh][ks2 * 32 + g * 8]);
#pragma unroll
            for (int nt = 0; nt < 4; ++nt) {
                const int rV = nt * 16 + qh;
                const int sl = (ks2 * 4 + g) ^ (rV & 7);
                bf16x8 vf = *reinterpret_cast<const bf16x8*>(&v_lds[cur][rV * 64 + sl * 8]);
                o[nt] = __builtin_amdgcn_mfma_f32_16x16x32_bf16(pa, vf, o[nt], 0, 0, 0);
            }
        }
        __syncthreads();
        cur ^= 1;
    }

    // normalize + store ctx (bf16) at [b*T+t][h*64 + d]
#pragma unroll
    for (int r = 0; r < 4; ++r) {
        const float linv = 1.0f / __shfl(l_s, g * 4 + r);
        const int trow = qbase + w * 16 + g * 4 + r;
#pragma unroll
        for (int nt = 0; nt < 4; ++nt)
            ctx[(size_t)(b * 2048 + trow) * 1024 + h * 64 + nt * 16 + qh] =
                f2b(o[nt][r] * linv);
    }
}

// ---------------------------------------------------------------------------
// GEMM2: out = ctx @ WoutT^T + bout   (bf16 in, fp32 out). 2-phase dbuf.
// ---------------------------------------------------------------------------
__global__ __launch_bounds__(256) void gemm2_kernel(
    const short* __restrict__ CTX, const short* __restrict__ WT,
    const float* __restrict__ bout, float* __restrict__ out) {
    __shared__ short a_lds[2][128 * 32];
    __shared__ short b_lds[2][128 * 32];
    const int tid = threadIdx.x;
    const int lane = tid & 63, w = tid >> 6;
    const int wr = w >> 1, wc = w & 1;
    const int m0 = blockIdx.y * 128, n0 = blockIdx.x * 128;
    f32x4 acc[4][4] = {};

    const int srow0 = tid >> 2, ssl = tid & 3;
    const int slc0 = (ssl ^ ((srow0 >> 1) & 3)) * 8;
    const int srow1 = srow0 + 64;
    const int slc1 = (ssl ^ ((srow1 >> 1) & 3)) * 8;

#define G2_STAGE(bufi, kk)                                                          \
    do {                                                                            \
        GLOAD_LDS16(CTX + (size_t)(m0 + srow0) * 1024 + (kk) + slc0,                \
                    &a_lds[bufi][(w * 64) * 8]);                                    \
        GLOAD_LDS16(WT + (size_t)(n0 + srow0) * 1024 + (kk) + slc0,                 \
                    &b_lds[bufi][(w * 64) * 8]);                                    \
        GLOAD_LDS16(CTX + (size_t)(m0 + srow1) * 1024 + (kk) + slc1,                \
                    &a_lds[bufi][(256 + w * 64) * 8]);                              \
        GLOAD_LDS16(WT + (size_t)(n0 + srow1) * 1024 + (kk) + slc1,                 \
                    &b_lds[bufi][(256 + w * 64) * 8]);                              \
    } while (0)

    G2_STAGE(0, 0);
    __syncthreads();
    int cur = 0;
    for (int k0 = 0; k0 < 1024; k0 += 32) {
        if (k0 + 32 < 1024) G2_STAGE(cur ^ 1, k0 + 32);
        bf16x8 af[4], bfv[4];
#pragma unroll
        for (int mi = 0; mi < 4; ++mi) {
            const int rA = wr * 64 + mi * 16 + (lane & 15);
            const int sl = (lane >> 4) ^ ((rA >> 1) & 3);
            af[mi] = *reinterpret_cast<const bf16x8*>(&a_lds[cur][rA * 32 + sl * 8]);
        }
#pragma unroll
        for (int nj = 0; nj < 4; ++nj) {
            const int rB = wc * 64 + nj * 16 + (lane & 15);
            const int sl = (lane >> 4) ^ ((rB >> 1) & 3);
            bfv[nj] = *reinterpret_cast<const bf16x8*>(&b_lds[cur][rB * 32 + sl * 8]);
        }
#pragma unroll
        for (int mi = 0; mi < 4; ++mi)
#pragma unroll
            for (int nj = 0; nj < 4; ++nj)
                acc[mi][nj] = __builtin_amdgcn_mfma_f32_16x16x32_bf16(af[mi], bfv[nj], acc[mi][nj], 0, 0, 0);
        __syncthreads();
        cur ^= 1;
    }

#pragma unroll
    for (int mi = 0; mi < 4; ++mi) {
#pragma unroll
        for (int nj = 0; nj < 4; ++nj) {
            const int row0 = m0 + wr * 64 + mi * 16 + ((lane >> 4) << 2);
            const int col  = n0 + wc * 64 + nj * 16 + (lane & 15);
            const float bias = bout[col];
#pragma unroll
            for (int r = 0; r < 4; ++r)
                out[(size_t)(row0 + r) * 1024 + col] = acc[mi][nj][r] + bias;
        }
    }
}

// ---------------------------------------------------------------------------
extern "C" void kernel_launch(void* const* d_in, const int* in_sizes, int n_in,
                              void* d_out, int out_size, void* d_ws, size_t ws_size,
                              hipStream_t stream) {
    const float* x    = (const float*)d_in[0];
    const float* Wqkv = (const float*)d_in[1];
    const float* bqkv = (const float*)d_in[2];
    const float* Wout = (const float*)d_in[3];
    const float* bout = (const float*)d_in[4];
    float* out = (float*)d_out;

    const size_t MB = 1u << 20;
    if (ws_size < 40 * MB) return;

    char* ws = (char*)d_ws;
    short* qb    = (short*)(ws + 0 * MB);    // [2][16][2048][64] bf16  (8 MB)
    short* kb    = (short*)(ws + 8 * MB);    // [2][16][2048][64] bf16  (8 MB)
    short* vtb   = (short*)(ws + 16 * MB);   // [2][16][64][2048] bf16  (8 MB)
    short* xbctx = (short*)(ws + 24 * MB);   // xb for gemm1, then ctx  (8 MB)
    short* wqkvT = (short*)(ws + 32 * MB);   // [3072][1024] bf16       (6 MB)
    short* woutT = (short*)(ws + 38 * MB);   // [1024][1024] bf16       (2 MB)

    xcvt_kernel<<<2048, 256, 0, stream>>>(x, xbctx);
    transpose_w_kernel<<<dim3(48, 16), 256, 0, stream>>>(Wqkv, wqkvT, 1024, 3072);
    transpose_w_kernel<<<dim3(16, 16), 256, 0, stream>>>(Wout, woutT, 1024, 1024);
    gemm1_kernel<<<dim3(24, 32), 256, 0, stream>>>(xbctx, wqkvT, bqkv, qb, kb, vtb);
    attn_kernel<<<dim3(16, 16, 2), 512, 0, stream>>>(qb, kb, vtb, xbctx);
    gemm2_kernel<<<dim3(8, 32), 256, 0, stream>>>(xbctx, woutT, bout, out);
}

// Round 5
// 198.093 us; speedup vs baseline: 1.5330x; 1.0894x over previous
//
#include <hip/hip_runtime.h>
#include <hip/hip_bf16.h>

// Problem constants: B=2, T=2048, D=1024, H=16, HD=64

typedef __attribute__((ext_vector_type(8))) short bf16x8;
typedef __attribute__((ext_vector_type(4))) float f32x4;
typedef __attribute__((ext_vector_type(16))) float f32x16;

#if __has_builtin(__builtin_amdgcn_exp2f)
#define EXP2(x) __builtin_amdgcn_exp2f(x)
#else
#define EXP2(x) exp2f(x)
#endif

__device__ __forceinline__ short f2b(float f) {
    __hip_bfloat16 h = __float2bfloat16(f);
    union { __hip_bfloat16 h; short s; } u; u.h = h;
    return u.s;
}

#define GLOAD_LDS16(gp, lp)                                                        \
    __builtin_amdgcn_global_load_lds(                                              \
        (const __attribute__((address_space(1))) unsigned int*)(gp),               \
        (__attribute__((address_space(3))) unsigned int*)(lp), 16, 0, 0)

// ---------------------------------------------------------------------------
// x fp32 -> bf16, 8 elements/thread
// ---------------------------------------------------------------------------
__global__ __launch_bounds__(256) void xcvt_kernel(
    const float* __restrict__ in, short* __restrict__ out) {
    const int i = (blockIdx.x * 256 + threadIdx.x) * 8;
    float4 v0 = *reinterpret_cast<const float4*>(in + i);
    float4 v1 = *reinterpret_cast<const float4*>(in + i + 4);
    union { short s[8]; uint4 q; } pk;
    pk.s[0] = f2b(v0.x); pk.s[1] = f2b(v0.y); pk.s[2] = f2b(v0.z); pk.s[3] = f2b(v0.w);
    pk.s[4] = f2b(v1.x); pk.s[5] = f2b(v1.y); pk.s[6] = f2b(v1.z); pk.s[7] = f2b(v1.w);
    *reinterpret_cast<uint4*>(out + i) = pk.q;
}

// ---------------------------------------------------------------------------
// Transpose + fp32->bf16 convert:  in[R][C] fp32  ->  out[C][R] bf16
// ---------------------------------------------------------------------------
__global__ __launch_bounds__(256) void transpose_w_kernel(
    const float* __restrict__ in, short* __restrict__ out, int R, int C) {
    __shared__ short lds[64][72];
    const int t = threadIdx.x;
    const int r0 = blockIdx.y * 64, c0 = blockIdx.x * 64;
    {
        const int ri = t >> 2, cb = (t & 3) * 16;
        const float* src = in + (size_t)(r0 + ri) * C + c0 + cb;
#pragma unroll
        for (int i = 0; i < 16; i += 4) {
            float4 v = *reinterpret_cast<const float4*>(src + i);
            lds[cb + i + 0][ri] = f2b(v.x);
            lds[cb + i + 1][ri] = f2b(v.y);
            lds[cb + i + 2][ri] = f2b(v.z);
            lds[cb + i + 3][ri] = f2b(v.w);
        }
    }
    __syncthreads();
    {
        const int co = t >> 2, rb = (t & 3) * 16;
        short* dst = out + (size_t)(c0 + co) * R + r0 + rb;
        *reinterpret_cast<uint4*>(dst)     = *reinterpret_cast<const uint4*>(&lds[co][rb]);
        *reinterpret_cast<uint4*>(dst + 8) = *reinterpret_cast<const uint4*>(&lds[co][rb + 8]);
    }
}

// ---------------------------------------------------------------------------
// GEMM1: qkv = xb @ WqkvT^T + bqkv   (bf16 in, fp32 acc)
// 128x128 tile, BK=32, 4 waves, 2-phase dbuf global_load_lds, XCD swizzle.
// Q pre-scaled by 0.125*log2(e). Epilogue: q,k -> [bh][t][64]; v -> [bh][64][t].
// ---------------------------------------------------------------------------
__global__ __launch_bounds__(256) void gemm1_kernel(
    const short* __restrict__ XB, const short* __restrict__ WT,
    const float* __restrict__ bqkv,
    short* __restrict__ qb, short* __restrict__ kb, short* __restrict__ vtb) {
    __shared__ short a_lds[2][128 * 32];
    __shared__ short b_lds[2][128 * 32];
    const int tid = threadIdx.x;
    const int lane = tid & 63, w = tid >> 6;
    const int wr = w >> 1, wc = w & 1;
    const int lin = blockIdx.x + 24 * blockIdx.y;     // nwg=768, 768%8==0
    const int swz = (lin & 7) * 96 + (lin >> 3);
    const int m0 = (swz / 24) * 128, n0 = (swz % 24) * 128;
    f32x4 acc[4][4] = {};

    const int srow0 = tid >> 2, ssl = tid & 3;
    const int slc0 = (ssl ^ ((srow0 >> 1) & 3)) * 8;
    const int srow1 = srow0 + 64;
    const int slc1 = (ssl ^ ((srow1 >> 1) & 3)) * 8;

#define G1_STAGE(bufi, kk)                                                          \
    do {                                                                            \
        GLOAD_LDS16(XB + (size_t)(m0 + srow0) * 1024 + (kk) + slc0,                 \
                    &a_lds[bufi][(w * 64) * 8]);                                    \
        GLOAD_LDS16(WT + (size_t)(n0 + srow0) * 1024 + (kk) + slc0,                 \
                    &b_lds[bufi][(w * 64) * 8]);                                    \
        GLOAD_LDS16(XB + (size_t)(m0 + srow1) * 1024 + (kk) + slc1,                 \
                    &a_lds[bufi][(256 + w * 64) * 8]);                              \
        GLOAD_LDS16(WT + (size_t)(n0 + srow1) * 1024 + (kk) + slc1,                 \
                    &b_lds[bufi][(256 + w * 64) * 8]);                              \
    } while (0)

    G1_STAGE(0, 0);
    __syncthreads();
    int cur = 0;
    for (int k0 = 0; k0 < 1024; k0 += 32) {
        if (k0 + 32 < 1024) G1_STAGE(cur ^ 1, k0 + 32);
        bf16x8 af[4], bfv[4];
#pragma unroll
        for (int mi = 0; mi < 4; ++mi) {
            const int rA = wr * 64 + mi * 16 + (lane & 15);
            const int sl = (lane >> 4) ^ ((rA >> 1) & 3);
            af[mi] = *reinterpret_cast<const bf16x8*>(&a_lds[cur][rA * 32 + sl * 8]);
        }
#pragma unroll
        for (int nj = 0; nj < 4; ++nj) {
            const int rB = wc * 64 + nj * 16 + (lane & 15);
            const int sl = (lane >> 4) ^ ((rB >> 1) & 3);
            bfv[nj] = *reinterpret_cast<const bf16x8*>(&b_lds[cur][rB * 32 + sl * 8]);
        }
#pragma unroll
        for (int mi = 0; mi < 4; ++mi)
#pragma unroll
            for (int nj = 0; nj < 4; ++nj)
                acc[mi][nj] = __builtin_amdgcn_mfma_f32_16x16x32_bf16(af[mi], bfv[nj], acc[mi][nj], 0, 0, 0);
        __syncthreads();
        cur ^= 1;
    }

    const float QSCL = 0.125f * 1.44269504088896340736f;   // 1/sqrt(64)*log2(e)
#pragma unroll
    for (int mi = 0; mi < 4; ++mi) {
#pragma unroll
        for (int nj = 0; nj < 4; ++nj) {
            const int row0 = m0 + wr * 64 + mi * 16 + ((lane >> 4) << 2);
            const int col  = n0 + wc * 64 + nj * 16 + (lane & 15);
            const float bias = bqkv[col];
            const int sec = col >> 10;
            const int h = (col & 1023) >> 6, d = col & 63;
            const int b = row0 >> 11;
            const int bh = b * 16 + h;
            if (sec == 2) {
                const int t0 = row0 & 2047;
                union { short s[4]; uint2 u; } pk;
#pragma unroll
                for (int r = 0; r < 4; ++r) pk.s[r] = f2b(acc[mi][nj][r] + bias);
                *reinterpret_cast<uint2*>(vtb + (size_t)(bh * 64 + d) * 2048 + t0) = pk.u;
            } else if (sec == 0) {
#pragma unroll
                for (int r = 0; r < 4; ++r) {
                    const int t = (row0 & 2047) + r;
                    qb[(size_t)(bh * 2048 + t) * 64 + d] = f2b((acc[mi][nj][r] + bias) * QSCL);
                }
            } else {
#pragma unroll
                for (int r = 0; r < 4; ++r) {
                    const int t = (row0 & 2047) + r;
                    kb[(size_t)(bh * 2048 + t) * 64 + d] = f2b(acc[mi][nj][r] + bias);
                }
            }
        }
    }
}

// ---------------------------------------------------------------------------
// Flash attention, 32x32x16 swapped structure with in-register P (T12).
// WG = 256 thr (4 waves x 32 q-rows), QBLK=128, KVBLK=64, K/V 2-phase dbuf.
// S^T = mfma(K,Q): lane owns 32 S-values of ONE q-row (col=lane&31) ->
// in-lane softmax + 1 shfl_xor(32); scalar per-lane m,l; defer-max THR=8
// (log2 domain, Q pre-scaled). P: cvt_pk pairs + v_permlane32_swap_b32
// builds PV B-frags in registers (no P LDS bounce).
// O^T = mfma(V^T, P^T): per-lane 1/l, packed uint2 stores.
// bh-grouped block swizzle: each XCD's L2 keeps 4 (b,h) K/V pairs resident.
// ---------------------------------------------------------------------------
__global__ __launch_bounds__(256) void attn_kernel(
    const short* __restrict__ qb, const short* __restrict__ kb,
    const short* __restrict__ vtb, short* __restrict__ ctx) {
    __shared__ short k_lds[2][64 * 64];
    __shared__ short v_lds[2][64 * 64];
    const int tid = threadIdx.x, lane = tid & 63, w = tid >> 6;
    const int q31 = lane & 31, hi = lane >> 5;

    // bh-grouped swizzle: dispatch d -> XCD d&7 owns bh in [4*(d&7), 4*(d&7)+4)
    const int dlin = blockIdx.x + 16 * (blockIdx.y + 16 * blockIdx.z);
    const int xcd = dlin & 7, ii = dlin >> 3;
    const int bh = xcd * 4 + (ii >> 4);
    const int qblk = ii & 15;
    const int b = bh >> 4, h = bh & 15;
    const int tq = qblk * 128 + w * 32 + q31;

    // Q B-frags (B-layout: col=lane&31, k=(lane>>5)*8+j): qf[s] = Q[tq][16s+8hi..]
    bf16x8 qf[4];
#pragma unroll
    for (int s = 0; s < 4; ++s)
        qf[s] = *reinterpret_cast<const bf16x8*>(
            qb + (size_t)(bh * 2048 + tq) * 64 + s * 16 + hi * 8);

    const int srow_l = lane >> 3, ssl = lane & 7;
    const int row_a = w * 8 + srow_l;          // rep 0 row
    const int row_b = 32 + w * 8 + srow_l;     // rep 1 row
    const int lc_a = (ssl ^ (row_a & 7)) * 8;
    const int lc_b = (ssl ^ (row_b & 7)) * 8;

#define ATT_STAGE(bufi, kv)                                                         \
    do {                                                                            \
        GLOAD_LDS16(kb + (size_t)(bh * 2048 + (kv) + row_a) * 64 + lc_a,            \
                    &k_lds[bufi][(w * 8) * 64]);                                    \
        GLOAD_LDS16(vtb + (size_t)(bh * 64 + row_a) * 2048 + (kv) + lc_a,           \
                    &v_lds[bufi][(w * 8) * 64]);                                    \
        GLOAD_LDS16(kb + (size_t)(bh * 2048 + (kv) + row_b) * 64 + lc_b,            \
                    &k_lds[bufi][(32 * 64) + (w * 8) * 64]);                        \
        GLOAD_LDS16(vtb + (size_t)(bh * 64 + row_b) * 2048 + (kv) + lc_b,           \
                    &v_lds[bufi][(32 * 64) + (w * 8) * 64]);                        \
    } while (0)

    f32x16 o0 = {}, o1 = {};
    float m_s = -1e30f, l_s = 0.f;

    ATT_STAGE(0, 0);
    __syncthreads();
    int cur = 0;
    for (int kv0 = 0; kv0 < 2048; kv0 += 64) {
        if (kv0 + 64 < 2048) ATT_STAGE(cur ^ 1, kv0 + 64);

        // S^T: sA0 = kv rows 0..31, sA1 = 32..63 (col = q31)
        f32x16 sA0 = {}, sA1 = {};
#pragma unroll
        for (int s = 0; s < 4; ++s) {
            {
                const int row = q31;
                const int sl = (2 * s + hi) ^ (row & 7);
                bf16x8 kf = *reinterpret_cast<const bf16x8*>(&k_lds[cur][row * 64 + sl * 8]);
                sA0 = __builtin_amdgcn_mfma_f32_32x32x16_bf16(kf, qf[s], sA0, 0, 0, 0);
            }
            {
                const int row = 32 + q31;
                const int sl = (2 * s + hi) ^ (row & 7);
                bf16x8 kf = *reinterpret_cast<const bf16x8*>(&k_lds[cur][row * 64 + sl * 8]);
                sA1 = __builtin_amdgcn_mfma_f32_32x32x16_bf16(kf, qf[s], sA1, 0, 0, 0);
            }
        }

        // row max: tree over 32 in-lane values + pair combine across hi
        float mA[8];
#pragma unroll
        for (int e = 0; e < 8; ++e)
            mA[e] = fmaxf(fmaxf(sA0[e], sA0[e + 8]), fmaxf(sA1[e], sA1[e + 8]));
        float mx = fmaxf(fmaxf(fmaxf(mA[0], mA[1]), fmaxf(mA[2], mA[3])),
                         fmaxf(fmaxf(mA[4], mA[5]), fmaxf(mA[6], mA[7])));
        mx = fmaxf(mx, __shfl_xor(mx, 32));

        const float mn = fmaxf(m_s, mx);
        if (__any(mn - m_s > 8.f)) {                      // defer-max (T13)
            const float alpha = EXP2(m_s - mn);
            m_s = mn;
            l_s *= alpha;
#pragma unroll
            for (int e = 0; e < 16; ++e) { o0[e] *= alpha; o1[e] *= alpha; }
        }

        // exp + pack to bf16 pairs: W[m] = cvt_pk(p[2m], p[2m+1])
        float rs = 0.f;
        int W0[8], W1[8];
#pragma unroll
        for (int m2 = 0; m2 < 8; ++m2) {
            float p0 = EXP2(sA0[2 * m2] - m_s);
            float p1 = EXP2(sA0[2 * m2 + 1] - m_s);
            rs += p0 + p1;
            asm("v_cvt_pk_bf16_f32 %0, %1, %2" : "=v"(W0[m2]) : "v"(p0), "v"(p1));
            float p2 = EXP2(sA1[2 * m2] - m_s);
            float p3 = EXP2(sA1[2 * m2 + 1] - m_s);
            rs += p2 + p3;
            asm("v_cvt_pk_bf16_f32 %0, %1, %2" : "=v"(W1[m2]) : "v"(p2), "v"(p3));
        }
        rs += __shfl_xor(rs, 32);
        l_s += rs;

        // PV: B-frag via permlane32_swap (lane hi=0 gets partner's lo-kv words)
#pragma unroll
        for (int s = 0; s < 4; ++s) {
            const int base = (s & 1) * 4;
            int x0, x1, y0, y1;
            if (s < 2) { x0 = W0[base]; x1 = W0[base + 1]; y0 = W0[base + 2]; y1 = W0[base + 3]; }
            else       { x0 = W1[base]; x1 = W1[base + 1]; y0 = W1[base + 2]; y1 = W1[base + 3]; }
            asm("v_permlane32_swap_b32 %0, %1" : "+v"(x0), "+v"(y0));
            asm("v_permlane32_swap_b32 %0, %1" : "+v"(x1), "+v"(y1));
            union { int w[4]; bf16x8 v; } pf;
            pf.w[0] = x0; pf.w[1] = x1; pf.w[2] = y0; pf.w[3] = y1;
            {
                const int row = q31;
                const int sl = (2 * s + hi) ^ (row & 7);
                bf16x8 vf = *reinterpret_cast<const bf16x8*>(&v_lds[cur][row * 64 + sl * 8]);
                o0 = __builtin_amdgcn_mfma_f32_32x32x16_bf16(vf, pf.v, o0, 0, 0, 0);
            }
            {
                const int row = 32 + q31;
                const int sl = (2 * s + hi) ^ (row & 7);
                bf16x8 vf = *reinterpret_cast<const bf16x8*>(&v_lds[cur][row * 64 + sl * 8]);
                o1 = __builtin_amdgcn_mfma_f32_32x32x16_bf16(vf, pf.v, o1, 0, 0, 0);
            }
        }
        __syncthreads();
        cur ^= 1;
    }

    // normalize + store: o(dt)[reg] -> d = (reg&3) + 8*(reg>>2) + 4*hi + 32*dt
    const float linv = 1.0f / l_s;
#pragma unroll
    for (int e = 0; e < 16; ++e) { o0[e] *= linv; o1[e] *= linv; }
    short* cbase = ctx + (size_t)(b * 2048 + tq) * 1024 + h * 64 + 4 * hi;
#pragma unroll
    for (int blk = 0; blk < 4; ++blk) {
        union { short s4[4]; uint2 u; } pk0, pk1;
#pragma unroll
        for (int r = 0; r < 4; ++r) {
            pk0.s4[r] = f2b(o0[4 * blk + r]);
            pk1.s4[r] = f2b(o1[4 * blk + r]);
        }
        *reinterpret_cast<uint2*>(cbase + 8 * blk)      = pk0.u;
        *reinterpret_cast<uint2*>(cbase + 32 + 8 * blk) = pk1.u;
    }
}

// ---------------------------------------------------------------------------
// GEMM2: out = ctx @ WoutT^T + bout   (bf16 in, fp32 out). 2-phase dbuf.
// ---------------------------------------------------------------------------
__global__ __launch_bounds__(256) void gemm2_kernel(
    const short* __restrict__ CTX, const short* __restrict__ WT,
    const float* __restrict__ bout, float* __restrict__ out) {
    __shared__ short a_lds[2][128 * 32];
    __shared__ short b_lds[2][128 * 32];
    const int tid = threadIdx.x;
    const int lane = tid & 63, w = tid >> 6;
    const int wr = w >> 1, wc = w & 1;
    const int lin = blockIdx.x + 8 * blockIdx.y;      // nwg=256
    const int swz = (lin & 7) * 32 + (lin >> 3);
    const int m0 = (swz >> 3) * 128, n0 = (swz & 7) * 128;
    f32x4 acc[4][4] = {};

    const int srow0 = tid >> 2, ssl = tid & 3;
    const int slc0 = (ssl ^ ((srow0 >> 1) & 3)) * 8;
    const int srow1 = srow0 + 64;
    const int slc1 = (ssl ^ ((srow1 >> 1) & 3)) * 8;

#define G2_STAGE(bufi, kk)                                                          \
    do {                                                                            \
        GLOAD_LDS16(CTX + (size_t)(m0 + srow0) * 1024 + (kk) + slc0,                \
                    &a_lds[bufi][(w * 64) * 8]);                                    \
        GLOAD_LDS16(WT + (size_t)(n0 + srow0) * 1024 + (kk) + slc0,                 \
                    &b_lds[bufi][(w * 64) * 8]);                                    \
        GLOAD_LDS16(CTX + (size_t)(m0 + srow1) * 1024 + (kk) + slc1,                \
                    &a_lds[bufi][(256 + w * 64) * 8]);                              \
        GLOAD_LDS16(WT + (size_t)(n0 + srow1) * 1024 + (kk) + slc1,                 \
                    &b_lds[bufi][(256 + w * 64) * 8]);                              \
    } while (0)

    G2_STAGE(0, 0);
    __syncthreads();
    int cur = 0;
    for (int k0 = 0; k0 < 1024; k0 += 32) {
        if (k0 + 32 < 1024) G2_STAGE(cur ^ 1, k0 + 32);
        bf16x8 af[4], bfv[4];
#pragma unroll
        for (int mi = 0; mi < 4; ++mi) {
            const int rA = wr * 64 + mi * 16 + (lane & 15);
            const int sl = (lane >> 4) ^ ((rA >> 1) & 3);
            af[mi] = *reinterpret_cast<const bf16x8*>(&a_lds[cur][rA * 32 + sl * 8]);
        }
#pragma unroll
        for (int nj = 0; nj < 4; ++nj) {
            const int rB = wc * 64 + nj * 16 + (lane & 15);
            const int sl = (lane >> 4) ^ ((rB >> 1) & 3);
            bfv[nj] = *reinterpret_cast<const bf16x8*>(&b_lds[cur][rB * 32 + sl * 8]);
        }
#pragma unroll
        for (int mi = 0; mi < 4; ++mi)
#pragma unroll
            for (int nj = 0; nj < 4; ++nj)
                acc[mi][nj] = __builtin_amdgcn_mfma_f32_16x16x32_bf16(af[mi], bfv[nj], acc[mi][nj], 0, 0, 0);
        __syncthreads();
        cur ^= 1;
    }

#pragma unroll
    for (int mi = 0; mi < 4; ++mi) {
#pragma unroll
        for (int nj = 0; nj < 4; ++nj) {
            const int row0 = m0 + wr * 64 + mi * 16 + ((lane >> 4) << 2);
            const int col  = n0 + wc * 64 + nj * 16 + (lane & 15);
            const float bias = bout[col];
#pragma unroll
            for (int r = 0; r < 4; ++r)
                out[(size_t)(row0 + r) * 1024 + col] = acc[mi][nj][r] + bias;
        }
    }
}

// ---------------------------------------------------------------------------
extern "C" void kernel_launch(void* const* d_in, const int* in_sizes, int n_in,
                              void* d_out, int out_size, void* d_ws, size_t ws_size,
                              hipStream_t stream) {
    const float* x    = (const float*)d_in[0];
    const float* Wqkv = (const float*)d_in[1];
    const float* bqkv = (const float*)d_in[2];
    const float* Wout = (const float*)d_in[3];
    const float* bout = (const float*)d_in[4];
    float* out = (float*)d_out;

    const size_t MB = 1u << 20;
    if (ws_size < 40 * MB) return;

    char* ws = (char*)d_ws;
    short* qb    = (short*)(ws + 0 * MB);    // [2][16][2048][64] bf16  (8 MB)
    short* kb    = (short*)(ws + 8 * MB);    // [2][16][2048][64] bf16  (8 MB)
    short* vtb   = (short*)(ws + 16 * MB);   // [2][16][64][2048] bf16  (8 MB)
    short* xbctx = (short*)(ws + 24 * MB);   // xb for gemm1, then ctx  (8 MB)
    short* wqkvT = (short*)(ws + 32 * MB);   // [3072][1024] bf16       (6 MB)
    short* woutT = (short*)(ws + 38 * MB);   // [1024][1024] bf16       (2 MB)

    xcvt_kernel<<<2048, 256, 0, stream>>>(x, xbctx);
    transpose_w_kernel<<<dim3(48, 16), 256, 0, stream>>>(Wqkv, wqkvT, 1024, 3072);
    transpose_w_kernel<<<dim3(16, 16), 256, 0, stream>>>(Wout, woutT, 1024, 1024);
    gemm1_kernel<<<dim3(24, 32), 256, 0, stream>>>(xbctx, wqkvT, bqkv, qb, kb, vtb);
    attn_kernel<<<dim3(16, 16, 2), 256, 0, stream>>>(qb, kb, vtb, xbctx);
    gemm2_kernel<<<dim3(8, 32), 256, 0, stream>>>(xbctx, woutT, bout, out);
}